// Round 1
// 4215.974 us; speedup vs baseline: 1.1920x; 1.1920x over previous
//
#include <hip/hip_runtime.h>
#include <cstdint>
#include <cstddef>

// ---------------------------------------------------------------------------
// Problem constants (from reference setup_inputs)
// ---------------------------------------------------------------------------
#define NC    10000      // cells
#define EE    320000     // edges per order
#define HID   256        // hidden
#define KHOP  10         // propagation hops
#define D_RNA 2000
#define D_ATAC 5000

static inline int cdiv(int a, int b) { return (a + b - 1) / b; }

// ---------------------------------------------------------------------------
// fW softmax: 4 rows (rna o0, rna o1, atac o0, atac o1) x 11
// ---------------------------------------------------------------------------
__global__ void fw_softmax_kernel(const float* __restrict__ fW_rna,
                                  const float* __restrict__ fW_atac,
                                  float* __restrict__ fw_soft) {
    int t = threadIdx.x;
    if (t < 4) {
        const float* src = (t < 2) ? (fW_rna + t * (KHOP + 1))
                                   : (fW_atac + (t - 2) * (KHOP + 1));
        float mx = -1e30f;
        for (int k = 0; k <= KHOP; k++) mx = fmaxf(mx, src[k]);
        float e[KHOP + 1];
        float s = 0.f;
        for (int k = 0; k <= KHOP; k++) { e[k] = expf(src[k] - mx); s += e[k]; }
        float inv = 1.f / s;
        for (int k = 0; k <= KHOP; k++) fw_soft[t * (KHOP + 1) + k] = e[k] * inv;
    }
}

// ---------------------------------------------------------------------------
// CSR build: histogram -> scan -> scatter (packed (col,val) records)
// ---------------------------------------------------------------------------
__global__ void hist_kernel(const int* __restrict__ row, int e_count,
                            int* __restrict__ counts) {
    int e = blockIdx.x * blockDim.x + threadIdx.x;
    if (e < e_count) atomicAdd(&counts[row[e]], 1);
}

__global__ __launch_bounds__(1024) void scan_kernel(const int* __restrict__ counts,
                                                    int* __restrict__ row_start,
                                                    int* __restrict__ cursor,
                                                    int n) {
    __shared__ int part[1024];
    int t = threadIdx.x;
    const int PER = (n + 1023) / 1024;
    int base = t * PER;
    int s = 0;
    for (int i = 0; i < PER; i++) {
        int idx = base + i;
        if (idx < n) s += counts[idx];
    }
    part[t] = s;
    __syncthreads();
    for (int off = 1; off < 1024; off <<= 1) {
        int v = (t >= off) ? part[t - off] : 0;
        __syncthreads();
        part[t] += v;
        __syncthreads();
    }
    int run = (t == 0) ? 0 : part[t - 1];
    for (int i = 0; i < PER; i++) {
        int idx = base + i;
        if (idx < n) {
            row_start[idx] = run;
            cursor[idx] = run;
            run += counts[idx];
        }
    }
    if (t == 1023) row_start[n] = part[1023];
}

__global__ void scatter_kernel(const int* __restrict__ row,
                               const int* __restrict__ col,
                               const float* __restrict__ val, int e_count,
                               int* __restrict__ cursor,
                               int2* __restrict__ ev) {
    int e = blockIdx.x * blockDim.x + threadIdx.x;
    if (e < e_count) {
        int p = atomicAdd(&cursor[row[e]], 1);
        ev[p] = make_int2(col[e], __float_as_int(val[e]));
    }
}

// ---------------------------------------------------------------------------
// Fused CSR SpMM for BOTH edge orders, float4-vectorized over 512 cols.
// Block b < NC -> order 0 row b ; block b >= NC -> order 1 row b-NC.
// 128 threads/block, each thread owns 4 consecutive cols (one float4).
// y = A_o @ x_o ; Z{rna,atac}[:, o*256 .. ] += fw[o][k] * y  (fused)
// ---------------------------------------------------------------------------
__global__ __launch_bounds__(128) void spmm2_kernel(
    const int* __restrict__ rs0, const int* __restrict__ rs1,
    const int2* __restrict__ ev0, const int2* __restrict__ ev1,
    const float4* __restrict__ x0, const float4* __restrict__ x1,
    float4* __restrict__ y0, float4* __restrict__ y1,
    float* __restrict__ zrna, float* __restrict__ zatac,
    const float* __restrict__ fw_soft, int k) {
    int b = blockIdx.x;
    int order = (b >= NC) ? 1 : 0;
    int n = order ? (b - NC) : b;
    const int* rs = order ? rs1 : rs0;
    const int2* ev = order ? ev1 : ev0;
    const float4* x = order ? x1 : x0;
    float4* y = order ? y1 : y0;

    int t = threadIdx.x;
    int s = rs[n];
    int e = rs[n + 1];
    float4 acc = make_float4(0.f, 0.f, 0.f, 0.f);
#pragma unroll 4
    for (int i = s; i < e; i++) {
        int2 cv = ev[i];                       // uniform -> scalar load
        float v = __int_as_float(cv.y);
        float4 xv = x[(size_t)cv.x * 128 + t]; // coalesced 1KB/wave gather
        acc.x += v * xv.x;
        acc.y += v * xv.y;
        acc.z += v * xv.z;
        acc.w += v * xv.w;
    }
    y[(size_t)n * 128 + t] = acc;

    float w;
    float* zp;
    if (t < 64) {   // wave-uniform branch
        w = fw_soft[order * (KHOP + 1) + k];
        zp = zrna + (size_t)n * 512 + order * 256 + t * 4;
    } else {
        w = fw_soft[(2 + order) * (KHOP + 1) + k];
        zp = zatac + (size_t)n * 512 + order * 256 + (t - 64) * 4;
    }
    float4 z = *(float4*)zp;
    z.x += w * acc.x;
    z.y += w * acc.y;
    z.z += w * acc.z;
    z.w += w * acc.w;
    *(float4*)zp = z;
}

// ---------------------------------------------------------------------------
// Attention fusion: attn = [z_rna|z_atac] @ Wa + ba ; softmax ; z = w0*zr+w1*za
// ---------------------------------------------------------------------------
__global__ __launch_bounds__(256) void attention_kernel(
    const float* __restrict__ z_rna, const float* __restrict__ z_atac,
    const float* __restrict__ Wa, const float* __restrict__ ba,
    float* __restrict__ z, float* __restrict__ weight) {
    int n = blockIdx.x;
    int t = threadIdx.x;
    float zr = z_rna[(size_t)n * 256 + t];
    float za = z_atac[(size_t)n * 256 + t];
    float p0 = zr * Wa[t * 2 + 0] + za * Wa[(256 + t) * 2 + 0];
    float p1 = zr * Wa[t * 2 + 1] + za * Wa[(256 + t) * 2 + 1];
    for (int off = 32; off > 0; off >>= 1) {
        p0 += __shfl_down(p0, off);
        p1 += __shfl_down(p1, off);
    }
    __shared__ float red0[4], red1[4];
    __shared__ float w0s, w1s;
    int wave = t >> 6, lane = t & 63;
    if (lane == 0) { red0[wave] = p0; red1[wave] = p1; }
    __syncthreads();
    if (t == 0) {
        float a0 = red0[0] + red0[1] + red0[2] + red0[3] + ba[0];
        float a1 = red1[0] + red1[1] + red1[2] + red1[3] + ba[1];
        float m = fmaxf(a0, a1);
        float e0 = expf(a0 - m), e1 = expf(a1 - m);
        float inv = 1.f / (e0 + e1);
        w0s = e0 * inv; w1s = e1 * inv;
        weight[(size_t)n * 2 + 0] = w0s;
        weight[(size_t)n * 2 + 1] = w1s;
    }
    __syncthreads();
    z[(size_t)n * 256 + t] = w0s * zr + w1s * za;
}

// ---------------------------------------------------------------------------
// Generalized tiled f32 GEMM. 256 threads. C[M,N] = A[M,K] @ B[K,N] + bias.
//  - BSPLIT: B columns [0,256) come from B0, [256,512) from B1 (both ldb).
//  - CSPLIT: C columns [0,256) -> C0, [256,512) -> C1 (col & 255, same ldc).
//  - ZINIT : additionally write Z[m*512+n] = fwp[(n>>8)*11] * value
//            (fuses the fw[0]*h accumulator init of the propagation).
//  - When TX==TY==16 the wave is mapped as an 8x8 patch so both As and Bs
//    ds_read_b128 are <=2-way bank conflicts (free).
// Assumes K%4==0, N%4==0 (all shapes here satisfy this).
// ---------------------------------------------------------------------------
template <int BM, int BN, int BK, int TM, int TN, bool RELU,
          bool BSPLIT, bool CSPLIT, bool ZINIT>
__global__ __launch_bounds__(256) void gemm_f32(
    const float* __restrict__ A, int lda,
    const float* __restrict__ B0, const float* __restrict__ B1, int ldb,
    const float* __restrict__ bias0, const float* __restrict__ bias1,
    float* __restrict__ C0, float* __restrict__ C1, int ldc,
    float* __restrict__ Z, const float* __restrict__ fwp,
    int M, int N, int K) {
    constexpr int TX = BN / TN;
    constexpr int TY = BM / TM;
    static_assert(TX * TY == 256, "thread tile mismatch");
    constexpr int LDA_S = BM + 4;
    constexpr int LDB_S = BN + 4;
    __shared__ __align__(16) float As[BK * LDA_S];
    __shared__ __align__(16) float Bs[BK * LDB_S];

    const int tid = threadIdx.x;
    int tx, ty;
    if constexpr (TX == 16 && TY == 16) {
        const int wid = tid >> 6, lane = tid & 63;
        tx = (lane & 7) + (wid & 1) * 8;
        ty = (lane >> 3) + ((wid >> 1) & 1) * 8;
    } else {
        tx = tid % TX;
        ty = tid / TX;
    }
    const int m0 = blockIdx.y * BM;
    const int n0 = blockIdx.x * BN;

    constexpr int A_L4 = (BM * BK) / 1024;  // float4 loads per thread
    constexpr int B_L4 = (BK * BN) / 1024;
    static_assert(A_L4 >= 1 && B_L4 >= 1, "tile too small for 256 threads");
    constexpr int KV = BK / 4;
    constexpr int NV = BN / 4;

    float acc[TM][TN];
#pragma unroll
    for (int i = 0; i < TM; i++)
#pragma unroll
        for (int j = 0; j < TN; j++) acc[i][j] = 0.f;

    for (int kt = 0; kt < K; kt += BK) {
        float4 a4[A_L4], b4[B_L4];
#pragma unroll
        for (int l = 0; l < A_L4; l++) {
            int idx = tid + l * 256;
            int ar = idx / KV, ak = (idx % KV) * 4;
            int mg = m0 + ar, kg = kt + ak;
            a4[l] = make_float4(0.f, 0.f, 0.f, 0.f);
            if (mg < M && kg < K)  // K%4==0 -> whole float4 in bounds
                a4[l] = *(const float4*)(A + (size_t)mg * lda + kg);
        }
#pragma unroll
        for (int l = 0; l < B_L4; l++) {
            int idx = tid + l * 256;
            int br = idx / NV, bc = (idx % NV) * 4;
            int kg = kt + br, ng = n0 + bc;
            b4[l] = make_float4(0.f, 0.f, 0.f, 0.f);
            if (kg < K && ng < N) {
                const float* Bp;
                if constexpr (BSPLIT) {
                    Bp = (ng < 256 ? B0 : B1) + (size_t)kg * ldb + (ng & 255);
                } else {
                    Bp = B0 + (size_t)kg * ldb + ng;
                }
                b4[l] = *(const float4*)Bp;
            }
        }

        __syncthreads();
#pragma unroll
        for (int l = 0; l < A_L4; l++) {
            int idx = tid + l * 256;
            int ar = idx / KV, ak = (idx % KV) * 4;
            As[(ak + 0) * LDA_S + ar] = a4[l].x;
            As[(ak + 1) * LDA_S + ar] = a4[l].y;
            As[(ak + 2) * LDA_S + ar] = a4[l].z;
            As[(ak + 3) * LDA_S + ar] = a4[l].w;
        }
#pragma unroll
        for (int l = 0; l < B_L4; l++) {
            int idx = tid + l * 256;
            int br = idx / NV, bc = (idx % NV) * 4;
            *(float4*)(Bs + br * LDB_S + bc) = b4[l];
        }
        __syncthreads();

#pragma unroll
        for (int kk = 0; kk < BK; kk++) {
            float a[TM], b[TN];
#pragma unroll
            for (int i = 0; i < TM; i += 4)
                *(float4*)&a[i] = *(const float4*)&As[kk * LDA_S + ty * TM + i];
#pragma unroll
            for (int j = 0; j < TN; j += 4)
                *(float4*)&b[j] = *(const float4*)&Bs[kk * LDB_S + tx * TN + j];
#pragma unroll
            for (int i = 0; i < TM; i++)
#pragma unroll
                for (int j = 0; j < TN; j++) acc[i][j] += a[i] * b[j];
        }
    }

    // epilogue
    float bb[TN];
#pragma unroll
    for (int j = 0; j < TN; j++) {
        int n = n0 + tx * TN + j;
        if (n < N) {
            if constexpr (BSPLIT)
                bb[j] = (n < 256) ? bias0[n] : bias1[n & 255];
            else
                bb[j] = bias0[n];
        } else
            bb[j] = 0.f;
    }
#pragma unroll
    for (int i = 0; i < TM; i++) {
        int m = m0 + ty * TM + i;
        if (m >= M) continue;
#pragma unroll
        for (int j = 0; j < TN; j += 4) {
            int n = n0 + tx * TN + j;
            if (n >= N) continue;  // N%4==0 -> whole float4 in bounds
            float4 v;
            v.x = acc[i][j + 0] + bb[j + 0];
            v.y = acc[i][j + 1] + bb[j + 1];
            v.z = acc[i][j + 2] + bb[j + 2];
            v.w = acc[i][j + 3] + bb[j + 3];
            if (RELU) {
                v.x = fmaxf(v.x, 0.f);
                v.y = fmaxf(v.y, 0.f);
                v.z = fmaxf(v.z, 0.f);
                v.w = fmaxf(v.w, 0.f);
            }
            float* Cp;
            int nc = n;
            if constexpr (CSPLIT) {
                Cp = (n < 256) ? C0 : C1;
                nc = n & 255;
            } else {
                Cp = C0;
            }
            *(float4*)(Cp + (size_t)m * ldc + nc) = v;
            if constexpr (ZINIT) {
                float wz = fwp[(n >> 8) * (KHOP + 1)];
                float4 zv = make_float4(wz * v.x, wz * v.y, wz * v.z, wz * v.w);
                *(float4*)(Z + (size_t)m * 512 + n) = zv;
            }
        }
    }
}

// ---------------------------------------------------------------------------
// Host orchestration
// ---------------------------------------------------------------------------
extern "C" void kernel_launch(void* const* d_in, const int* in_sizes, int n_in,
                              void* d_out, int out_size, void* d_ws, size_t ws_size,
                              hipStream_t stream) {
    const float* X_rna   = (const float*)d_in[0];
    const float* X_atac  = (const float*)d_in[1];
    const int*   row_in[2] = {(const int*)d_in[2], (const int*)d_in[5]};
    const int*   col_in[2] = {(const int*)d_in[3], (const int*)d_in[6]};
    const float* val_in[2] = {(const float*)d_in[4], (const float*)d_in[7]};
    const float* Wi_rna  = (const float*)d_in[8];
    const float* bi_rna  = (const float*)d_in[9];
    const float* fW_rna  = (const float*)d_in[10];
    const float* Wo_rna  = (const float*)d_in[11];
    const float* bo_rna  = (const float*)d_in[12];
    const float* Wi_atac = (const float*)d_in[13];
    const float* bi_atac = (const float*)d_in[14];
    const float* fW_atac = (const float*)d_in[15];
    const float* Wo_atac = (const float*)d_in[16];
    const float* bo_atac = (const float*)d_in[17];
    const float* Wa      = (const float*)d_in[18];
    const float* ba      = (const float*)d_in[19];
    const float* Wd1_rna = (const float*)d_in[20];
    const float* bd1_rna = (const float*)d_in[21];
    const float* Wd2_rna = (const float*)d_in[22];
    const float* bd2_rna = (const float*)d_in[23];
    const float* Wd1_atac = (const float*)d_in[24];
    const float* bd1_atac = (const float*)d_in[25];
    const float* Wd2_atac = (const float*)d_in[26];
    const float* bd2_atac = (const float*)d_in[27];

    float* out = (float*)d_out;
    // output tuple layout (flat, return order)
    float* o_z        = out;                    // [N,256]
    float* o_z_rna    = out + 2560000;          // [N,256]
    float* o_z_atac   = out + 5120000;          // [N,256]
    float* o_weight   = out + 7680000;          // [N,2]
    float* o_rna_rec  = out + 7700000;          // [N,2000]
    float* o_atac_rec = out + 27700000;         // [N,5000]

    // scratch hosted inside the (not-yet-written) atac_rec output region:
    // all six buffers are dead before the final decoder GEMM writes atac_rec.
    float* xk00  = o_atac_rec;                  // [N,512] order0 ping
    float* xk01  = o_atac_rec + 1 * 5120000;    // [N,512] order0 pong
    float* xk10  = o_atac_rec + 2 * 5120000;    // [N,512] order1 ping
    float* xk11  = o_atac_rec + 3 * 5120000;    // [N,512] order1 pong
    float* Zrna  = o_atac_rec + 4 * 5120000;    // [N,512] concat input for Wo_rna
    float* Zatac = o_atac_rec + 5 * 5120000;    // [N,512] concat input for Wo_atac

    // ws scratch (~26 MB)
    char* w = (char*)d_ws;
    float* fw_soft = (float*)w;  w += 256;
    float* d1_rna  = (float*)w;  w += (size_t)NC * 256 * 4;   // 10.24 MB
    float* d1_atac = (float*)w;  w += (size_t)NC * 256 * 4;   // 10.24 MB
    int* counts[2]; int* rstart[2]; int* cursor[2]; int2* ev[2];
    for (int o = 0; o < 2; o++) {
        counts[o] = (int*)w;   w += 40960;
        rstart[o] = (int*)w;   w += 40960;
        cursor[o] = (int*)w;   w += 40960;
        ev[o]     = (int2*)w;  w += (size_t)EE * 8;
    }

    // 1. fW softmax
    fw_softmax_kernel<<<1, 64, 0, stream>>>(fW_rna, fW_atac, fw_soft);

    // 2. CSR build for both edge orders
    for (int o = 0; o < 2; o++) {
        hipMemsetAsync(counts[o], 0, NC * sizeof(int), stream);
        hist_kernel<<<cdiv(EE, 256), 256, 0, stream>>>(row_in[o], EE, counts[o]);
        scan_kernel<<<1, 1024, 0, stream>>>(counts[o], rstart[o], cursor[o], NC);
        scatter_kernel<<<cdiv(EE, 256), 256, 0, stream>>>(
            row_in[o], col_in[o], val_in[o], EE, cursor[o], ev[o]);
    }

    // 3. encoder GEMMs, fused over the two orders (N=512 = [o0|o1]),
    //    C-split routes o0 cols to xk0 and o1 cols to xk1, ZINIT fuses the
    //    acc = fw[0]*h init into the epilogue.
    {
        dim3 g(4, cdiv(NC, 128));
        // rna modality -> xk{0,1}[:, 0:256], Zrna (all 512 cols)
        gemm_f32<128, 128, 16, 8, 8, false, true, true, true><<<g, 256, 0, stream>>>(
            X_rna, D_RNA, Wi_rna, Wi_rna + (size_t)D_RNA * HID, HID,
            bi_rna, bi_rna + HID,
            xk00, xk10, 512,
            Zrna, fw_soft,
            NC, 512, D_RNA);
        // atac modality -> xk{0,1}[:, 256:512], Zatac
        gemm_f32<128, 128, 16, 8, 8, false, true, true, true><<<g, 256, 0, stream>>>(
            X_atac, D_ATAC, Wi_atac, Wi_atac + (size_t)D_ATAC * HID, HID,
            bi_atac, bi_atac + HID,
            xk00 + 256, xk10 + 256, 512,
            Zatac, fw_soft + 2 * (KHOP + 1),
            NC, 512, D_ATAC);
    }

    // 4. K-hop propagation, both orders fused per launch (2*NC blocks)
    {
        float* s0 = xk00; float* d0 = xk01;
        float* s1 = xk10; float* d1 = xk11;
        for (int k = 1; k <= KHOP; k++) {
            spmm2_kernel<<<2 * NC, 128, 0, stream>>>(
                rstart[0], rstart[1], ev[0], ev[1],
                (const float4*)s0, (const float4*)s1,
                (float4*)d0, (float4*)d1,
                Zrna, Zatac, fw_soft, k);
            float* t;
            t = s0; s0 = d0; d0 = t;
            t = s1; s1 = d1; d1 = t;
        }
    }

    // 5. Wo GEMMs -> z_rna, z_atac
    {
        dim3 g(4, cdiv(NC, 128));  // N=256, BN=64
        gemm_f32<128, 64, 16, 8, 4, false, false, false, false><<<g, 256, 0, stream>>>(
            Zrna, 512, Wo_rna, nullptr, HID, bo_rna, nullptr,
            o_z_rna, nullptr, HID, nullptr, nullptr, NC, HID, 512);
        gemm_f32<128, 64, 16, 8, 4, false, false, false, false><<<g, 256, 0, stream>>>(
            Zatac, 512, Wo_atac, nullptr, HID, bo_atac, nullptr,
            o_z_atac, nullptr, HID, nullptr, nullptr, NC, HID, 512);
    }

    // 6. attention fusion -> z, weight
    attention_kernel<<<NC, 256, 0, stream>>>(o_z_rna, o_z_atac, Wa, ba, o_z, o_weight);

    // 7. decoder hidden layers, fused (shared A = z, N=512 = [rna|atac], relu)
    {
        dim3 g(4, cdiv(NC, 128));
        gemm_f32<128, 128, 16, 8, 8, true, true, true, false><<<g, 256, 0, stream>>>(
            o_z, HID, Wd1_rna, Wd1_atac, HID, bd1_rna, bd1_atac,
            d1_rna, d1_atac, HID, nullptr, nullptr, NC, 512, HID);
    }

    // 8. decoder output layers (atac one overwrites the scratch region last)
    {
        dim3 g1(cdiv(D_RNA, 128), cdiv(NC, 128));
        gemm_f32<128, 128, 16, 8, 8, false, false, false, false><<<g1, 256, 0, stream>>>(
            d1_rna, HID, Wd2_rna, nullptr, D_RNA, bd2_rna, nullptr,
            o_rna_rec, nullptr, D_RNA, nullptr, nullptr, NC, D_RNA, HID);
        dim3 g2(cdiv(D_ATAC, 128), cdiv(NC, 128));
        gemm_f32<128, 128, 16, 8, 8, false, false, false, false><<<g2, 256, 0, stream>>>(
            d1_atac, HID, Wd2_atac, nullptr, D_ATAC, bd2_atac, nullptr,
            o_atac_rec, nullptr, D_ATAC, nullptr, nullptr, NC, D_ATAC, HID);
    }
}

// Round 3
// 3730.478 us; speedup vs baseline: 1.3471x; 1.1301x over previous
//
#include <hip/hip_runtime.h>
#include <cstdint>
#include <cstddef>

// ---------------------------------------------------------------------------
// Problem constants (from reference setup_inputs)
// ---------------------------------------------------------------------------
#define NC    10000      // cells
#define EE    320000     // edges per order
#define HID   256        // hidden
#define KHOP  10         // propagation hops
#define D_RNA 2000
#define D_ATAC 5000

static inline int cdiv(int a, int b) { return (a + b - 1) / b; }

// ---------------------------------------------------------------------------
// fW softmax: 4 rows (rna o0, rna o1, atac o0, atac o1) x 11
// ---------------------------------------------------------------------------
__global__ void fw_softmax_kernel(const float* __restrict__ fW_rna,
                                  const float* __restrict__ fW_atac,
                                  float* __restrict__ fw_soft) {
    int t = threadIdx.x;
    if (t < 4) {
        const float* src = (t < 2) ? (fW_rna + t * (KHOP + 1))
                                   : (fW_atac + (t - 2) * (KHOP + 1));
        float mx = -1e30f;
        for (int k = 0; k <= KHOP; k++) mx = fmaxf(mx, src[k]);
        float e[KHOP + 1];
        float s = 0.f;
        for (int k = 0; k <= KHOP; k++) { e[k] = expf(src[k] - mx); s += e[k]; }
        float inv = 1.f / s;
        for (int k = 0; k <= KHOP; k++) fw_soft[t * (KHOP + 1) + k] = e[k] * inv;
    }
}

// ---------------------------------------------------------------------------
// CSR build: histogram -> scan -> scatter (packed (col,val) records)
// ---------------------------------------------------------------------------
__global__ void hist_kernel(const int* __restrict__ row, int e_count,
                            int* __restrict__ counts) {
    int e = blockIdx.x * blockDim.x + threadIdx.x;
    if (e < e_count) atomicAdd(&counts[row[e]], 1);
}

__global__ __launch_bounds__(1024) void scan_kernel(const int* __restrict__ counts,
                                                    int* __restrict__ row_start,
                                                    int* __restrict__ cursor,
                                                    int n) {
    __shared__ int part[1024];
    int t = threadIdx.x;
    const int PER = (n + 1023) / 1024;
    int base = t * PER;
    int s = 0;
    for (int i = 0; i < PER; i++) {
        int idx = base + i;
        if (idx < n) s += counts[idx];
    }
    part[t] = s;
    __syncthreads();
    for (int off = 1; off < 1024; off <<= 1) {
        int v = (t >= off) ? part[t - off] : 0;
        __syncthreads();
        part[t] += v;
        __syncthreads();
    }
    int run = (t == 0) ? 0 : part[t - 1];
    for (int i = 0; i < PER; i++) {
        int idx = base + i;
        if (idx < n) {
            row_start[idx] = run;
            cursor[idx] = run;
            run += counts[idx];
        }
    }
    if (t == 1023) row_start[n] = part[1023];
}

__global__ void scatter_kernel(const int* __restrict__ row,
                               const int* __restrict__ col,
                               const float* __restrict__ val, int e_count,
                               int* __restrict__ cursor,
                               int2* __restrict__ ev) {
    int e = blockIdx.x * blockDim.x + threadIdx.x;
    if (e < e_count) {
        int p = atomicAdd(&cursor[row[e]], 1);
        ev[p] = make_int2(col[e], __float_as_int(val[e]));
    }
}

// ---------------------------------------------------------------------------
// Fused CSR SpMM for BOTH edge orders, float4-vectorized over 512 cols.
// Block b < NC -> order 0 row b ; block b >= NC -> order 1 row b-NC.
// ---------------------------------------------------------------------------
__global__ __launch_bounds__(128) void spmm2_kernel(
    const int* __restrict__ rs0, const int* __restrict__ rs1,
    const int2* __restrict__ ev0, const int2* __restrict__ ev1,
    const float4* __restrict__ x0, const float4* __restrict__ x1,
    float4* __restrict__ y0, float4* __restrict__ y1,
    float* __restrict__ zrna, float* __restrict__ zatac,
    const float* __restrict__ fw_soft, int k) {
    int b = blockIdx.x;
    int order = (b >= NC) ? 1 : 0;
    int n = order ? (b - NC) : b;
    const int* rs = order ? rs1 : rs0;
    const int2* ev = order ? ev1 : ev0;
    const float4* x = order ? x1 : x0;
    float4* y = order ? y1 : y0;

    int t = threadIdx.x;
    int s = rs[n];
    int e = rs[n + 1];
    float4 acc = make_float4(0.f, 0.f, 0.f, 0.f);
#pragma unroll 4
    for (int i = s; i < e; i++) {
        int2 cv = ev[i];                       // uniform -> one cache line
        float v = __int_as_float(cv.y);
        float4 xv = x[(size_t)cv.x * 128 + t]; // coalesced 1KB/wave gather
        acc.x += v * xv.x;
        acc.y += v * xv.y;
        acc.z += v * xv.z;
        acc.w += v * xv.w;
    }
    y[(size_t)n * 128 + t] = acc;

    float w;
    float* zp;
    if (t < 64) {   // wave-uniform branch
        w = fw_soft[order * (KHOP + 1) + k];
        zp = zrna + (size_t)n * 512 + order * 256 + t * 4;
    } else {
        w = fw_soft[(2 + order) * (KHOP + 1) + k];
        zp = zatac + (size_t)n * 512 + order * 256 + (t - 64) * 4;
    }
    float4 z = *(float4*)zp;
    z.x += w * acc.x;
    z.y += w * acc.y;
    z.z += w * acc.z;
    z.w += w * acc.w;
    *(float4*)zp = z;
}

// ---------------------------------------------------------------------------
// Attention fusion
// ---------------------------------------------------------------------------
__global__ __launch_bounds__(256) void attention_kernel(
    const float* __restrict__ z_rna, const float* __restrict__ z_atac,
    const float* __restrict__ Wa, const float* __restrict__ ba,
    float* __restrict__ z, float* __restrict__ weight) {
    int n = blockIdx.x;
    int t = threadIdx.x;
    float zr = z_rna[(size_t)n * 256 + t];
    float za = z_atac[(size_t)n * 256 + t];
    float p0 = zr * Wa[t * 2 + 0] + za * Wa[(256 + t) * 2 + 0];
    float p1 = zr * Wa[t * 2 + 1] + za * Wa[(256 + t) * 2 + 1];
    for (int off = 32; off > 0; off >>= 1) {
        p0 += __shfl_down(p0, off);
        p1 += __shfl_down(p1, off);
    }
    __shared__ float red0[4], red1[4];
    __shared__ float w0s, w1s;
    int wave = t >> 6, lane = t & 63;
    if (lane == 0) { red0[wave] = p0; red1[wave] = p1; }
    __syncthreads();
    if (t == 0) {
        float a0 = red0[0] + red0[1] + red0[2] + red0[3] + ba[0];
        float a1 = red1[0] + red1[1] + red1[2] + red1[3] + ba[1];
        float m = fmaxf(a0, a1);
        float e0 = expf(a0 - m), e1 = expf(a1 - m);
        float inv = 1.f / (e0 + e1);
        w0s = e0 * inv; w1s = e1 * inv;
        weight[(size_t)n * 2 + 0] = w0s;
        weight[(size_t)n * 2 + 1] = w1s;
    }
    __syncthreads();
    z[(size_t)n * 256 + t] = w0s * zr + w1s * za;
}

// ---------------------------------------------------------------------------
// split-K reduce: sum SK partial planes [M,512], add bias, C-split route to
// xk0/xk1 (propagation ping buffers), and write Z = fw[order][0] * h.
// ---------------------------------------------------------------------------
__global__ __launch_bounds__(128) void splitk_reduce_kernel(
    const float4* __restrict__ P,
    const float* __restrict__ bias0, const float* __restrict__ bias1,
    float* __restrict__ C0, float* __restrict__ C1,
    float* __restrict__ Z, const float* __restrict__ fwp, int sk) {
    int m = blockIdx.x, t = threadIdx.x;
    size_t idx = (size_t)m * 128 + t;
    const size_t plane = (size_t)NC * 128;
    float4 s = P[idx];
    for (int z = 1; z < sk; z++) {
        float4 p = P[idx + (size_t)z * plane];
        s.x += p.x; s.y += p.y; s.z += p.z; s.w += p.w;
    }
    int n = t * 4;
    const float* bp = (t < 64) ? (bias0 + n) : (bias1 + (n - 256));
    s.x += bp[0]; s.y += bp[1]; s.z += bp[2]; s.w += bp[3];
    float* Cp = ((t < 64) ? C0 : C1) + (size_t)m * 512 + (n & 255);
    *(float4*)Cp = s;
    float wz = fwp[(t >> 6) * (KHOP + 1)];
    float4 zv = make_float4(wz * s.x, wz * s.y, wz * s.z, wz * s.w);
    *(float4*)(Z + (size_t)m * 512 + n) = zv;
}

// ---------------------------------------------------------------------------
// Generalized tiled f32 GEMM. 256 threads. C[M,N] = A[M,K] @ B[K,N] + bias.
//  - BSPLIT: B columns [0,256) from B0, [256,512) from B1 (both ldb).
//  - CSPLIT: C columns [0,256) -> C0, [256,512) -> C1 (col & 255, same ldc).
//  - SPLITK: blockIdx.z = K-chunk; write raw partial (no bias) to plane z of P.
//  - PAIR  : blockIdx.z = 1 selects (A1, B1, bias1, C1) — two GEMMs, 1 launch.
//  - When TX==TY==16 the wave is an 8x8 lane patch -> As/Bs ds_read_b128 are
//    <=2-way bank conflicts (free on CDNA4).
// ---------------------------------------------------------------------------
template <int BM, int BN, int BK, int TM, int TN, bool RELU,
          bool BSPLIT, bool CSPLIT, bool SPLITK, bool PAIR>
__global__ __launch_bounds__(256) void gemm_f32(
    const float* __restrict__ A, const float* __restrict__ A1, int lda,
    const float* __restrict__ B0, const float* __restrict__ B1, int ldb,
    const float* __restrict__ bias0, const float* __restrict__ bias1,
    float* __restrict__ C0, float* __restrict__ C1, int ldc,
    float* __restrict__ P, int Kc,
    int M, int N, int K) {
    constexpr int TX = BN / TN;
    constexpr int TY = BM / TM;
    static_assert(TX * TY == 256, "thread tile mismatch");
    constexpr int LDA_S = BM + 4;
    constexpr int LDB_S = BN + 4;
    __shared__ __align__(16) float As[BK * LDA_S];
    __shared__ __align__(16) float Bs[BK * LDB_S];

    const int tid = threadIdx.x;
    int tx, ty;
    if constexpr (TX == 16 && TY == 16) {
        const int wid = tid >> 6, lane = tid & 63;
        tx = (lane & 7) + (wid & 1) * 8;
        ty = (lane >> 3) + ((wid >> 1) & 1) * 8;
    } else {
        tx = tid % TX;
        ty = tid / TX;
    }
    const int m0 = blockIdx.y * BM;
    const int n0 = blockIdx.x * BN;

    int kb = 0, ke = K;
    if constexpr (SPLITK) {
        kb = blockIdx.z * Kc;
        ke = min(K, kb + Kc);
    }
    const float* Ap = A;
    const float* Bp0 = B0;
    const float* biasp = bias0;
    float* Cp0 = C0;
    if constexpr (PAIR) {
        if (blockIdx.z) { Ap = A1; Bp0 = B1; biasp = bias1; Cp0 = C1; }
    }

    constexpr int A_L4 = (BM * BK) / 1024;  // float4 loads per thread
    constexpr int B_L4 = (BK * BN) / 1024;
    static_assert(A_L4 >= 1 && B_L4 >= 1, "tile too small for 256 threads");
    constexpr int KV = BK / 4;
    constexpr int NV = BN / 4;

    float acc[TM][TN];
#pragma unroll
    for (int i = 0; i < TM; i++)
#pragma unroll
        for (int j = 0; j < TN; j++) acc[i][j] = 0.f;

    for (int kt = kb; kt < ke; kt += BK) {
        float4 a4[A_L4], b4[B_L4];
#pragma unroll
        for (int l = 0; l < A_L4; l++) {
            int idx = tid + l * 256;
            int ar = idx / KV, ak = (idx % KV) * 4;
            int mg = m0 + ar, kg = kt + ak;
            a4[l] = make_float4(0.f, 0.f, 0.f, 0.f);
            if (mg < M && kg < ke)  // kb,ke,K all %4==0 -> whole float4 ok
                a4[l] = *(const float4*)(Ap + (size_t)mg * lda + kg);
        }
#pragma unroll
        for (int l = 0; l < B_L4; l++) {
            int idx = tid + l * 256;
            int br = idx / NV, bc = (idx % NV) * 4;
            int kg = kt + br, ng = n0 + bc;
            b4[l] = make_float4(0.f, 0.f, 0.f, 0.f);
            if (kg < ke && ng < N) {
                const float* Bp;
                if constexpr (BSPLIT) {
                    Bp = (ng < 256 ? B0 : B1) + (size_t)kg * ldb + (ng & 255);
                } else {
                    Bp = Bp0 + (size_t)kg * ldb + ng;
                }
                b4[l] = *(const float4*)Bp;
            }
        }

        __syncthreads();
#pragma unroll
        for (int l = 0; l < A_L4; l++) {
            int idx = tid + l * 256;
            int ar = idx / KV, ak = (idx % KV) * 4;
            As[(ak + 0) * LDA_S + ar] = a4[l].x;
            As[(ak + 1) * LDA_S + ar] = a4[l].y;
            As[(ak + 2) * LDA_S + ar] = a4[l].z;
            As[(ak + 3) * LDA_S + ar] = a4[l].w;
        }
#pragma unroll
        for (int l = 0; l < B_L4; l++) {
            int idx = tid + l * 256;
            int br = idx / NV, bc = (idx % NV) * 4;
            *(float4*)(Bs + br * LDB_S + bc) = b4[l];
        }
        __syncthreads();

#pragma unroll
        for (int kk = 0; kk < BK; kk++) {
            float a[TM], b[TN];
#pragma unroll
            for (int i = 0; i < TM; i += 4)
                *(float4*)&a[i] = *(const float4*)&As[kk * LDA_S + ty * TM + i];
#pragma unroll
            for (int j = 0; j < TN; j += 4)
                *(float4*)&b[j] = *(const float4*)&Bs[kk * LDB_S + tx * TN + j];
#pragma unroll
            for (int i = 0; i < TM; i++)
#pragma unroll
                for (int j = 0; j < TN; j++) acc[i][j] += a[i] * b[j];
        }
    }

    if constexpr (SPLITK) {
        // raw partial (no bias) to plane blockIdx.z of P
        float* Pp = P + (size_t)blockIdx.z * M * ldc;
#pragma unroll
        for (int i = 0; i < TM; i++) {
            int m = m0 + ty * TM + i;
            if (m >= M) continue;
#pragma unroll
            for (int j = 0; j < TN; j += 4) {
                int n = n0 + tx * TN + j;
                if (n >= N) continue;
                float4 v = make_float4(acc[i][j + 0], acc[i][j + 1],
                                       acc[i][j + 2], acc[i][j + 3]);
                *(float4*)(Pp + (size_t)m * ldc + n) = v;
            }
        }
        return;
    }

    // epilogue
    float bb[TN];
#pragma unroll
    for (int j = 0; j < TN; j++) {
        int n = n0 + tx * TN + j;
        if (n < N) {
            if constexpr (BSPLIT)
                bb[j] = (n < 256) ? bias0[n] : bias1[n & 255];
            else
                bb[j] = biasp[n];
        } else
            bb[j] = 0.f;
    }
#pragma unroll
    for (int i = 0; i < TM; i++) {
        int m = m0 + ty * TM + i;
        if (m >= M) continue;
#pragma unroll
        for (int j = 0; j < TN; j += 4) {
            int n = n0 + tx * TN + j;
            if (n >= N) continue;  // N%4==0 -> whole float4 in bounds
            float4 v;
            v.x = acc[i][j + 0] + bb[j + 0];
            v.y = acc[i][j + 1] + bb[j + 1];
            v.z = acc[i][j + 2] + bb[j + 2];
            v.w = acc[i][j + 3] + bb[j + 3];
            if (RELU) {
                v.x = fmaxf(v.x, 0.f);
                v.y = fmaxf(v.y, 0.f);
                v.z = fmaxf(v.z, 0.f);
                v.w = fmaxf(v.w, 0.f);
            }
            float* Cp;
            int nc = n;
            if constexpr (CSPLIT) {
                Cp = (n < 256) ? C0 : C1;
                nc = n & 255;
            } else {
                Cp = Cp0;
            }
            *(float4*)(Cp + (size_t)m * ldc + nc) = v;
        }
    }
}

// ---------------------------------------------------------------------------
// Host orchestration
// ---------------------------------------------------------------------------
extern "C" void kernel_launch(void* const* d_in, const int* in_sizes, int n_in,
                              void* d_out, int out_size, void* d_ws, size_t ws_size,
                              hipStream_t stream) {
    const float* X_rna   = (const float*)d_in[0];
    const float* X_atac  = (const float*)d_in[1];
    const int*   row_in[2] = {(const int*)d_in[2], (const int*)d_in[5]};
    const int*   col_in[2] = {(const int*)d_in[3], (const int*)d_in[6]};
    const float* val_in[2] = {(const float*)d_in[4], (const float*)d_in[7]};
    const float* Wi_rna  = (const float*)d_in[8];
    const float* bi_rna  = (const float*)d_in[9];
    const float* fW_rna  = (const float*)d_in[10];
    const float* Wo_rna  = (const float*)d_in[11];
    const float* bo_rna  = (const float*)d_in[12];
    const float* Wi_atac = (const float*)d_in[13];
    const float* bi_atac = (const float*)d_in[14];
    const float* fW_atac = (const float*)d_in[15];
    const float* Wo_atac = (const float*)d_in[16];
    const float* bo_atac = (const float*)d_in[17];
    const float* Wa      = (const float*)d_in[18];
    const float* ba      = (const float*)d_in[19];
    const float* Wd1_rna = (const float*)d_in[20];
    const float* bd1_rna = (const float*)d_in[21];
    const float* Wd2_rna = (const float*)d_in[22];
    const float* bd2_rna = (const float*)d_in[23];
    const float* Wd1_atac = (const float*)d_in[24];
    const float* bd1_atac = (const float*)d_in[25];
    const float* Wd2_atac = (const float*)d_in[26];
    const float* bd2_atac = (const float*)d_in[27];

    float* out = (float*)d_out;
    // output tuple layout (flat, return order)
    float* o_z        = out;                    // [N,256]
    float* o_z_rna    = out + 2560000;          // [N,256]
    float* o_z_atac   = out + 5120000;          // [N,256]
    float* o_weight   = out + 7680000;          // [N,2]
    float* o_rna_rec  = out + 7700000;          // [N,2000]  (20M floats)
    float* o_atac_rec = out + 27700000;         // [N,5000]  (50M floats)

    // scratch hosted inside not-yet-written output regions:
    //  - o_atac_rec (50M floats): 6 x [N,512] buffers, dead before step 8b.
    //  - o_rna_rec (20M floats): 3 x [N,512] split-K partials, dead after
    //    the encoder reduces (step 3), written by step 8a.
    float* xk00  = o_atac_rec;                  // [N,512] order0 ping
    float* xk01  = o_atac_rec + 1 * 5120000;    // [N,512] order0 pong
    float* xk10  = o_atac_rec + 2 * 5120000;    // [N,512] order1 ping
    float* xk11  = o_atac_rec + 3 * 5120000;    // [N,512] order1 pong
    float* Zrna  = o_atac_rec + 4 * 5120000;    // [N,512] concat for Wo_rna
    float* Zatac = o_atac_rec + 5 * 5120000;    // [N,512] concat for Wo_atac
    float* Pk    = o_rna_rec;                   // 3 x [N,512] split-K partials

    // ws scratch (~26 MB)
    char* w = (char*)d_ws;
    float* fw_soft = (float*)w;  w += 256;
    float* d1_rna  = (float*)w;  w += (size_t)NC * 256 * 4;   // 10.24 MB
    float* d1_atac = (float*)w;  w += (size_t)NC * 256 * 4;   // 10.24 MB
    int* counts[2]; int* rstart[2]; int* cursor[2]; int2* ev[2];
    for (int o = 0; o < 2; o++) {
        counts[o] = (int*)w;   w += 40960;
        rstart[o] = (int*)w;   w += 40960;
        cursor[o] = (int*)w;   w += 40960;
        ev[o]     = (int2*)w;  w += (size_t)EE * 8;
    }

    // 1. fW softmax
    fw_softmax_kernel<<<1, 64, 0, stream>>>(fW_rna, fW_atac, fw_soft);

    // 2. CSR build for both edge orders
    for (int o = 0; o < 2; o++) {
        hipMemsetAsync(counts[o], 0, NC * sizeof(int), stream);
        hist_kernel<<<cdiv(EE, 256), 256, 0, stream>>>(row_in[o], EE, counts[o]);
        scan_kernel<<<1, 1024, 0, stream>>>(counts[o], rstart[o], cursor[o], NC);
        scatter_kernel<<<cdiv(EE, 256), 256, 0, stream>>>(
            row_in[o], col_in[o], val_in[o], EE, cursor[o], ev[o]);
    }

    // 3. encoder GEMMs, fused over orders (N=512=[o0|o1]) AND split-K (SK=3)
    //    partial planes -> reduce adds bias, routes C-split, inits Z=fw[0]*h.
    {
        dim3 g(4, cdiv(NC, 128), 3);
        // rna modality: K=2000, Kc=672 (multiple of 16)
        gemm_f32<128, 128, 16, 8, 8, false, true, false, true, false>
            <<<g, 256, 0, stream>>>(
                X_rna, nullptr, D_RNA,
                Wi_rna, Wi_rna + (size_t)D_RNA * HID, HID,
                nullptr, nullptr, nullptr, nullptr, 512,
                Pk, 672, NC, 512, D_RNA);
        splitk_reduce_kernel<<<NC, 128, 0, stream>>>(
            (const float4*)Pk, bi_rna, bi_rna + HID,
            xk00, xk10, Zrna, fw_soft, 3);
        // atac modality: K=5000, Kc=1680 (multiple of 16)
        gemm_f32<128, 128, 16, 8, 8, false, true, false, true, false>
            <<<g, 256, 0, stream>>>(
                X_atac, nullptr, D_ATAC,
                Wi_atac, Wi_atac + (size_t)D_ATAC * HID, HID,
                nullptr, nullptr, nullptr, nullptr, 512,
                Pk, 1680, NC, 512, D_ATAC);
        splitk_reduce_kernel<<<NC, 128, 0, stream>>>(
            (const float4*)Pk, bi_atac, bi_atac + HID,
            xk00 + 256, xk10 + 256, Zatac, fw_soft + 2 * (KHOP + 1), 3);
    }

    // 4. K-hop propagation, both orders fused per launch (2*NC blocks)
    {
        float* s0 = xk00; float* d0 = xk01;
        float* s1 = xk10; float* d1 = xk11;
        for (int k = 1; k <= KHOP; k++) {
            spmm2_kernel<<<2 * NC, 128, 0, stream>>>(
                rstart[0], rstart[1], ev[0], ev[1],
                (const float4*)s0, (const float4*)s1,
                (float4*)d0, (float4*)d1,
                Zrna, Zatac, fw_soft, k);
            float* t;
            t = s0; s0 = d0; d0 = t;
            t = s1; s1 = d1; d1 = t;
        }
    }

    // 5. Wo GEMMs (paired into one launch via blockIdx.z) -> z_rna, z_atac
    {
        dim3 g(4, cdiv(NC, 128), 2);
        gemm_f32<128, 64, 16, 8, 4, false, false, false, false, true>
            <<<g, 256, 0, stream>>>(
                Zrna, Zatac, 512,
                Wo_rna, Wo_atac, HID,
                bo_rna, bo_atac,
                o_z_rna, o_z_atac, HID,
                nullptr, 0, NC, HID, 512);
    }

    // 6. attention fusion -> z, weight
    attention_kernel<<<NC, 256, 0, stream>>>(o_z_rna, o_z_atac, Wa, ba, o_z, o_weight);

    // 7. decoder hidden layers, fused (shared A = z, N=512=[rna|atac], relu)
    {
        dim3 g(8, cdiv(NC, 128));
        gemm_f32<128, 64, 16, 8, 4, true, true, true, false, false>
            <<<g, 256, 0, stream>>>(
                o_z, nullptr, HID,
                Wd1_rna, Wd1_atac, HID,
                bd1_rna, bd1_atac,
                d1_rna, d1_atac, HID,
                nullptr, 0, NC, 512, HID);
    }

    // 8. decoder output layers (8a overwrites the partial region, 8b the
    //    xk/Z scratch region — both dead by now)
    {
        dim3 g1(cdiv(D_RNA, 128), cdiv(NC, 128));
        gemm_f32<128, 128, 16, 8, 8, false, false, false, false, false>
            <<<g1, 256, 0, stream>>>(
                d1_rna, nullptr, HID,
                Wd2_rna, nullptr, D_RNA,
                bd2_rna, nullptr,
                o_rna_rec, nullptr, D_RNA,
                nullptr, 0, NC, D_RNA, HID);
        dim3 g2(cdiv(D_ATAC, 128), cdiv(NC, 128));
        gemm_f32<128, 128, 16, 8, 8, false, false, false, false, false>
            <<<g2, 256, 0, stream>>>(
                d1_atac, nullptr, HID,
                Wd2_atac, nullptr, D_ATAC,
                bd2_atac, nullptr,
                o_atac_rec, nullptr, D_ATAC,
                nullptr, 0, NC, D_ATAC, HID);
    }
}